// Round 1
// baseline (87.392 us; speedup 1.0000x reference)
//
#include <hip/hip_runtime.h>

// SoftCountPixels: x (B,3,H,W) fp32, P (32,3) fp32
// Y[b,p] = mean over pixels of exp(-||x[b,:,h,w]-P[p,:]||_2 / (2*0.3))

#define NPRO    32
#define HW      65536       // 256*256
#define THREADS 256
#define BPB     32          // blocks per batch
#define KITER   (HW / (BPB * THREADS * 4))   // = 2 float4 iterations per thread

__global__ __launch_bounds__(THREADS) void soft_count_kernel(
    const float* __restrict__ x, const float* __restrict__ P,
    float* __restrict__ out)
{
    __shared__ float sP[NPRO * 3];
    __shared__ float sred[4][NPRO];

    const int tid = threadIdx.x;
    if (tid < NPRO * 3) sP[tid] = P[tid];
    __syncthreads();

    const int b   = blockIdx.x / BPB;
    const int blk = blockIdx.x % BPB;

    const float* xr = x + (size_t)b * 3 * HW;   // channel 0 plane
    const float* xg = xr + HW;                  // channel 1 plane
    const float* xb = xr + 2 * HW;              // channel 2 plane

    float acc[NPRO];
#pragma unroll
    for (int p = 0; p < NPRO; ++p) acc[p] = 0.0f;

    const int base = blk * (THREADS * 4 * KITER);

#pragma unroll
    for (int k = 0; k < KITER; ++k) {
        const int idx = base + k * (THREADS * 4) + tid * 4;  // lane-contiguous float4
        const float4 r4 = *(const float4*)(xr + idx);
        const float4 g4 = *(const float4*)(xg + idx);
        const float4 b4 = *(const float4*)(xb + idx);
        const float rr[4] = {r4.x, r4.y, r4.z, r4.w};
        const float gg[4] = {g4.x, g4.y, g4.z, g4.w};
        const float bb[4] = {b4.x, b4.y, b4.z, b4.w};

#pragma unroll
        for (int p = 0; p < NPRO; ++p) {
            const float p0 = sP[p * 3 + 0];  // uniform-address LDS broadcast
            const float p1 = sP[p * 3 + 1];
            const float p2 = sP[p * 3 + 2];
            float s = 0.0f;
#pragma unroll
            for (int j = 0; j < 4; ++j) {
                const float d0 = rr[j] - p0;
                const float d1 = gg[j] - p1;
                const float d2 = bb[j] - p2;
                const float n2 = d0 * d0 + d1 * d1 + d2 * d2;
                const float nrm = sqrtf(n2);
                s += __expf(nrm * (-1.0f / 0.6f));   // exp(-norm/(2*0.3))
            }
            acc[p] += s;
        }
    }

    // per-wave shuffle reduction (wave = 64 on gfx950)
    const int lane = tid & 63;
    const int wv   = tid >> 6;
#pragma unroll
    for (int p = 0; p < NPRO; ++p) {
        float v = acc[p];
#pragma unroll
        for (int off = 32; off >= 1; off >>= 1)
            v += __shfl_down(v, off, 64);
        if (lane == 0) sred[wv][p] = v;
    }
    __syncthreads();

    if (tid < NPRO) {
        const float v = sred[0][tid] + sred[1][tid] + sred[2][tid] + sred[3][tid];
        atomicAdd(&out[b * NPRO + tid], v * (1.0f / (float)HW));
    }
}

__global__ void zero_out_kernel(float* out, int n) {
    const int i = blockIdx.x * blockDim.x + threadIdx.x;
    if (i < n) out[i] = 0.0f;
}

extern "C" void kernel_launch(void* const* d_in, const int* in_sizes, int n_in,
                              void* d_out, int out_size, void* d_ws, size_t ws_size,
                              hipStream_t stream) {
    const float* x = (const float*)d_in[0];
    const float* P = (const float*)d_in[1];
    float* out = (float*)d_out;

    const int nb = in_sizes[0] / (3 * HW);   // batch = 16

    zero_out_kernel<<<(out_size + 255) / 256, 256, 0, stream>>>(out, out_size);
    soft_count_kernel<<<nb * BPB, THREADS, 0, stream>>>(x, P, out);
}

// Round 2
// 77.458 us; speedup vs baseline: 1.1282x; 1.1282x over previous
//
#include <hip/hip_runtime.h>

// SoftCountPixels: x (B,3,H,W) fp32, P (32,3) fp32
// Y[b,p] = (1/HW) * sum_pixels exp(-||x[b,:,h,w]-P[p,:]||_2 / (2*0.3))
// exp(-n/0.6) computed as exp2(n * C), C = -log2(e)/0.6

#define NPRO    32
#define HW      65536       // 256*256
#define THREADS 256
#define BPB     64          // blocks per batch image; 4 pixels per thread

__global__ __launch_bounds__(THREADS) void soft_count_kernel(
    const float* __restrict__ x, const float* __restrict__ P,
    float* __restrict__ out)
{
    __shared__ float sP[NPRO * 3];
    __shared__ float sred[4][NPRO];

    const int tid = threadIdx.x;
    if (tid < NPRO * 3) sP[tid] = P[tid];
    __syncthreads();

    const int b   = blockIdx.x / BPB;
    const int blk = blockIdx.x % BPB;

    const float* base = x + (size_t)b * 3 * HW;
    const int idx = blk * (THREADS * 4) + tid * 4;   // lane-contiguous float4

    const float4 r4 = *(const float4*)(base + idx);           // channel 0
    const float4 g4 = *(const float4*)(base + HW + idx);      // channel 1
    const float4 b4 = *(const float4*)(base + 2 * HW + idx);  // channel 2
    const float rr[4] = {r4.x, r4.y, r4.z, r4.w};
    const float gg[4] = {g4.x, g4.y, g4.z, g4.w};
    const float bb[4] = {b4.x, b4.y, b4.z, b4.w};

    const float C = -2.4044917f;   // -log2(e)/0.6

    float acc[NPRO];
#pragma unroll
    for (int p = 0; p < NPRO; ++p) {
        const float p0 = sP[p * 3 + 0];  // uniform-address LDS broadcast
        const float p1 = sP[p * 3 + 1];
        const float p2 = sP[p * 3 + 2];
        float s = 0.0f;
#pragma unroll
        for (int j = 0; j < 4; ++j) {
            const float d0 = rr[j] - p0;
            const float d1 = gg[j] - p1;
            const float d2 = bb[j] - p2;
            const float n2 = fmaf(d2, d2, fmaf(d1, d1, d0 * d0));
            const float nrm = __builtin_amdgcn_sqrtf(n2);     // 1x v_sqrt_f32
            s += __builtin_amdgcn_exp2f(nrm * C);             // 1x v_exp_f32
        }
        acc[p] = s;
    }

    // per-wave shuffle reduction (wave = 64 on gfx950)
    const int lane = tid & 63;
    const int wv   = tid >> 6;
#pragma unroll
    for (int p = 0; p < NPRO; ++p) {
        float v = acc[p];
#pragma unroll
        for (int off = 32; off >= 1; off >>= 1)
            v += __shfl_down(v, off, 64);
        if (lane == 0) sred[wv][p] = v;
    }
    __syncthreads();

    if (tid < NPRO) {
        const float v = sred[0][tid] + sred[1][tid] + sred[2][tid] + sred[3][tid];
        atomicAdd(&out[b * NPRO + tid], v * (1.0f / (float)HW));
    }
}

extern "C" void kernel_launch(void* const* d_in, const int* in_sizes, int n_in,
                              void* d_out, int out_size, void* d_ws, size_t ws_size,
                              hipStream_t stream) {
    const float* x = (const float*)d_in[0];
    const float* P = (const float*)d_in[1];
    float* out = (float*)d_out;

    const int nb = in_sizes[0] / (3 * HW);   // batch = 16

    hipMemsetAsync(out, 0, (size_t)out_size * sizeof(float), stream);
    soft_count_kernel<<<nb * BPB, THREADS, 0, stream>>>(x, P, out);
}

// Round 3
// 75.236 us; speedup vs baseline: 1.1616x; 1.0295x over previous
//
#include <hip/hip_runtime.h>

// SoftCountPixels: x (B,3,H,W) fp32, P (32,3) fp32
// Y[b,p] = (1/HW) * sum_pixels exp(-||x[b,:,h,w]-P[p,:]||_2 / (2*0.3))
// Trick: pre-scale x,P by A = log2(e)/0.6 so per-combo work is
//   exp2(-sqrt(n2_scaled)), negation free via v_exp_f32 source modifier.

#define NPRO    32
#define HW      65536       // 256*256
#define THREADS 256
#define BPB     32          // blocks per batch image; 8 pixels per thread

__global__ __launch_bounds__(THREADS) void soft_count_kernel(
    const float* __restrict__ x, const float* __restrict__ P,
    float* __restrict__ out)
{
    __shared__ float sP[NPRO * 3];
    __shared__ float sred[4][NPRO];

    const float A = 2.4044917f;   // log2(e) / 0.6

    const int tid = threadIdx.x;
    if (tid < NPRO * 3) sP[tid] = P[tid] * A;   // pre-scaled prototypes
    __syncthreads();

    const int b   = blockIdx.x / BPB;
    const int blk = blockIdx.x % BPB;

    const float* base = x + (size_t)b * 3 * HW;

    // 8 pixels per thread: two lane-contiguous float4 loads per channel
    float rr[8], gg[8], bb[8];
#pragma unroll
    for (int k = 0; k < 2; ++k) {
        const int idx = blk * (THREADS * 8) + k * (THREADS * 4) + tid * 4;
        const float4 r4 = *(const float4*)(base + idx);
        const float4 g4 = *(const float4*)(base + HW + idx);
        const float4 b4 = *(const float4*)(base + 2 * HW + idx);
        rr[k*4+0] = r4.x * A; rr[k*4+1] = r4.y * A; rr[k*4+2] = r4.z * A; rr[k*4+3] = r4.w * A;
        gg[k*4+0] = g4.x * A; gg[k*4+1] = g4.y * A; gg[k*4+2] = g4.z * A; gg[k*4+3] = g4.w * A;
        bb[k*4+0] = b4.x * A; bb[k*4+1] = b4.y * A; bb[k*4+2] = b4.z * A; bb[k*4+3] = b4.w * A;
    }

    float acc[NPRO];
#pragma unroll
    for (int p = 0; p < NPRO; ++p) {
        const float p0 = sP[p * 3 + 0];  // uniform-address LDS broadcast
        const float p1 = sP[p * 3 + 1];
        const float p2 = sP[p * 3 + 2];
        float s = 0.0f;
#pragma unroll
        for (int j = 0; j < 8; ++j) {
            const float d0 = rr[j] - p0;
            const float d1 = gg[j] - p1;
            const float d2 = bb[j] - p2;
            const float n2 = fmaf(d2, d2, fmaf(d1, d1, d0 * d0));
            // exp2(-sqrt(n2)): v_sqrt_f32 + v_exp_f32 with free -src modifier
            s += __builtin_amdgcn_exp2f(-__builtin_amdgcn_sqrtf(n2));
        }
        acc[p] = s;
    }

    // per-wave shuffle reduction (wave = 64 on gfx950)
    const int lane = tid & 63;
    const int wv   = tid >> 6;
#pragma unroll
    for (int p = 0; p < NPRO; ++p) {
        float v = acc[p];
#pragma unroll
        for (int off = 32; off >= 1; off >>= 1)
            v += __shfl_down(v, off, 64);
        if (lane == 0) sred[wv][p] = v;
    }
    __syncthreads();

    if (tid < NPRO) {
        const float v = sred[0][tid] + sred[1][tid] + sred[2][tid] + sred[3][tid];
        atomicAdd(&out[b * NPRO + tid], v * (1.0f / (float)HW));
    }
}

extern "C" void kernel_launch(void* const* d_in, const int* in_sizes, int n_in,
                              void* d_out, int out_size, void* d_ws, size_t ws_size,
                              hipStream_t stream) {
    const float* x = (const float*)d_in[0];
    const float* P = (const float*)d_in[1];
    float* out = (float*)d_out;

    const int nb = in_sizes[0] / (3 * HW);   // batch = 16

    hipMemsetAsync(out, 0, (size_t)out_size * sizeof(float), stream);
    soft_count_kernel<<<nb * BPB, THREADS, 0, stream>>>(x, P, out);
}